// Round 1
// 379.963 us; speedup vs baseline: 1.0319x; 1.0319x over previous
//
#include <hip/hip_runtime.h>
#include <math.h>

typedef _Float16 f16;
typedef _Float16 f16x8 __attribute__((ext_vector_type(8)));
typedef _Float16 f16x4 __attribute__((ext_vector_type(4)));
typedef float    f32x4 __attribute__((ext_vector_type(4)));

// Problem constants: N=16384, D=4096, E=64, top_k=2.
constexpr int D_DIM   = 4096;
constexpr int E_DIM   = 64;
constexpr int BM      = 32;              // rows per block
constexpr int BK      = 64;              // 2 MFMA k-steps of 32
constexpr int NT      = 256;             // 4 waves: 2 k-halves x 2 row-groups
constexpr int KHALVES = 2;               // in-block split-K
constexpr int DK      = D_DIM / KHALVES; // 2048 per half
constexpr int KT      = DK / BK;         // 32 t-steps
constexpr int LDT     = BK + 8;          // 72 f16/row -> 2-way banks only (free)
constexpr int LDL     = E_DIM + 1;       // 65 -> conflict-free row scan

// Exact power-of-2 scaling keeps hi/lo residuals in f16 normal range.
constexpr float XSCALE  = 8.0f;
constexpr float WSCALE  = 256.0f;
constexpr float UNSCALE = 1.0f / 2048.0f;

// ---- kernel 0: pack W*256 -> f16 hi/lo planes in workspace (unchanged) ----
__global__ __launch_bounds__(NT) void pack_w(const float* __restrict__ W,
                                             f16* __restrict__ whi,
                                             f16* __restrict__ wlo) {
    const int i = (blockIdx.x * NT + threadIdx.x) * 4;
    const float4 w = *(const float4*)(W + i);
    const float v[4] = {w.x * WSCALE, w.y * WSCALE, w.z * WSCALE, w.w * WSCALE};
    f16x4 hv, lv;
#pragma unroll
    for (int j = 0; j < 4; ++j) {
        const f16 h = (f16)v[j];
        hv[j] = h;
        lv[j] = (f16)(v[j] - (float)h);
    }
    *(f16x4*)(whi + i) = hv;
    *(f16x4*)(wlo + i) = lv;
}

// ---- kernel 1: fused GEMM (in-block split-K) + top-2 + softmax + gates ----
// Block: 32 rows, full K=4096. Wave wv: half = wv>>1 (k-half), rg = wv&1
// (16-row group). Partials reduced in LDS; no global partials, no 3rd kernel.
__global__ __launch_bounds__(NT, 2) void moe_gate_fused(
    const float* __restrict__ x, const f16* __restrict__ whi,
    const f16* __restrict__ wlo, const float* __restrict__ b,
    float* __restrict__ out, int N)
{
    __shared__ alignas(16) f16 Wh[KHALVES][E_DIM * LDT];  // 2 x 9216 B
    __shared__ alignas(16) f16 Wl[KHALVES][E_DIM * LDT];  // 2 x 9216 B
    __shared__ float Ls[BM * LDL];                        // 8320 B logits
    __shared__ float aux[4 * BM];                         // i1,i2,p1,p2

    const int tid  = threadIdx.x;
    const int row0 = blockIdx.x * BM;

    // W staging coords: thread covers slot (we, ks2) for BOTH k-half tiles
    const int ks2 = tid & 3;            // 16-f16 slot pair within BK
    const int we  = tid >> 2;           // expert row 0..63

    // mfma coords
    const int lane = tid & 63;
    const int wv   = tid >> 6;
    const int half = wv >> 1;           // k-half 0/1
    const int rg   = wv & 1;            // row group 0/1
    const int r0   = rg * 16;
    const int m    = lane & 15;
    const int quad = lane >> 4;
    const int koff = half * DK;

    f32x4 acc[4] = {{0,0,0,0},{0,0,0,0},{0,0,0,0},{0,0,0,0}};

    f16x8 whr[KHALVES][2], wlr[KHALVES][2];
    auto loadW = [&](int t) {
#pragma unroll
        for (int h = 0; h < KHALVES; ++h) {
            const size_t o = (size_t)we * D_DIM + h * DK + t * BK + ks2 * 16;
            whr[h][0] = *(const f16x8*)(whi + o);
            whr[h][1] = *(const f16x8*)(whi + o + 8);
            wlr[h][0] = *(const f16x8*)(wlo + o);
            wlr[h][1] = *(const f16x8*)(wlo + o + 8);
        }
    };
    auto storeW = [&]() {
#pragma unroll
        for (int h = 0; h < KHALVES; ++h) {
            *(f16x8*)&Wh[h][we * LDT + ks2 * 16]     = whr[h][0];
            *(f16x8*)&Wh[h][we * LDT + ks2 * 16 + 8] = whr[h][1];
            *(f16x8*)&Wl[h][we * LDT + ks2 * 16]     = wlr[h][0];
            *(f16x8*)&Wl[h][we * LDT + ks2 * 16 + 8] = wlr[h][1];
        }
    };

    // A: lane owns x row (row0+r0+m), k-slice quad*8..+7 of each 32-k step
    const float* xrow = x + (size_t)(row0 + r0 + m) * D_DIM + koff + quad * 8;

    float4 xc[2][2], xn[2][2];
    auto loadX = [&](float4 d[2][2], int t) {
#pragma unroll
        for (int kk = 0; kk < 2; ++kk) {
            const float* p = xrow + t * BK + kk * 32;
            d[kk][0] = ((const float4*)p)[0];
            d[kk][1] = ((const float4*)p)[1];
        }
    };

    loadW(0);
    loadX(xc, 0);
    storeW();
    __syncthreads();

    for (int t = 0; t < KT; ++t) {
        if (t + 1 < KT) { loadW(t + 1); loadX(xn, t + 1); }

#pragma unroll
        for (int kk = 0; kk < 2; ++kk) {
            const float v[8] = {xc[kk][0].x * XSCALE, xc[kk][0].y * XSCALE,
                                xc[kk][0].z * XSCALE, xc[kk][0].w * XSCALE,
                                xc[kk][1].x * XSCALE, xc[kk][1].y * XSCALE,
                                xc[kk][1].z * XSCALE, xc[kk][1].w * XSCALE};
            f16x8 ah, al;
#pragma unroll
            for (int j = 0; j < 8; ++j) {
                const f16 h = (f16)v[j];
                ah[j] = h;
                al[j] = (f16)(v[j] - (float)h);
            }
            const int ko = kk * 32 + quad * 8;
#pragma unroll
            for (int ct = 0; ct < 4; ++ct) {
                const f16x8 bh = *(const f16x8*)&Wh[half][(ct * 16 + m) * LDT + ko];
                const f16x8 bl = *(const f16x8*)&Wl[half][(ct * 16 + m) * LDT + ko];
                acc[ct] = __builtin_amdgcn_mfma_f32_16x16x32_f16(ah, bh, acc[ct], 0, 0, 0);
                acc[ct] = __builtin_amdgcn_mfma_f32_16x16x32_f16(al, bh, acc[ct], 0, 0, 0);
                acc[ct] = __builtin_amdgcn_mfma_f32_16x16x32_f16(ah, bl, acc[ct], 0, 0, 0);
            }
        }
        __syncthreads();
        if (t + 1 < KT) {
            storeW();
#pragma unroll
            for (int kk = 0; kk < 2; ++kk) { xc[kk][0] = xn[kk][0]; xc[kk][1] = xn[kk][1]; }
        }
        __syncthreads();
    }

    // ---- in-block split-K reduction (C-layout: col=lane&15, row=quad*4+reg) ----
    if (half == 1) {
#pragma unroll
        for (int ct = 0; ct < 4; ++ct)
#pragma unroll
            for (int reg = 0; reg < 4; ++reg)
                Ls[(r0 + quad * 4 + reg) * LDL + ct * 16 + m] = acc[ct][reg];
    }
    __syncthreads();
    if (half == 0) {
#pragma unroll
        for (int ct = 0; ct < 4; ++ct)
#pragma unroll
            for (int reg = 0; reg < 4; ++reg) {
                const int r = r0 + quad * 4 + reg;
                const int e = ct * 16 + m;
                Ls[r * LDL + e] = (acc[ct][reg] + Ls[r * LDL + e]) * UNSCALE + b[e];
            }
    }
    __syncthreads();

    // ---- top-2 + softmax (strict '>' = lax.top_k tie-break) ----
    if (tid < BM) {
        const float* lr = &Ls[tid * LDL];
        float v1 = -INFINITY, v2 = -INFINITY;
        int i1 = 0, i2 = 0;
        for (int e = 0; e < E_DIM; ++e) {
            const float v = lr[e];
            if (v > v1)      { v2 = v1; i2 = i1; v1 = v; i1 = e; }
            else if (v > v2) { v2 = v;  i2 = e; }
        }
        const float ex = expf(v2 - v1);
        const float dn = 1.0f + ex;
        aux[tid]          = (float)i1;
        aux[BM + tid]     = (float)i2;
        aux[2 * BM + tid] = 1.0f / dn;
        aux[3 * BM + tid] = ex / dn;
        const size_t basei = (size_t)N * E_DIM + (size_t)(row0 + tid) * 2;
        out[basei]     = (float)i1;   // indices as float values (fp32 out buffer)
        out[basei + 1] = (float)i2;
    }
    __syncthreads();

    // ---- gate scatter: 32 rows x 16 float4 = 512 slots, 256 threads x 2 ----
#pragma unroll
    for (int p = 0; p < 2; ++p) {
        const int f4 = p * NT + tid;
        const int r  = f4 >> 4;
        const int c4 = f4 & 15;
        const int i1 = (int)aux[r];
        const int i2 = (int)aux[BM + r];
        const float p1 = aux[2 * BM + r];
        const float p2 = aux[3 * BM + r];
        const int e = c4 * 4;
        float4 g;
        g.x = (e + 0 == i1) ? p1 : (e + 0 == i2) ? p2 : 0.0f;
        g.y = (e + 1 == i1) ? p1 : (e + 1 == i2) ? p2 : 0.0f;
        g.z = (e + 2 == i1) ? p1 : (e + 2 == i2) ? p2 : 0.0f;
        g.w = (e + 3 == i1) ? p1 : (e + 3 == i2) ? p2 : 0.0f;
        *(float4*)(out + (size_t)(row0 + r) * E_DIM + e) = g;
    }
}

extern "C" void kernel_launch(void* const* d_in, const int* in_sizes, int n_in,
                              void* d_out, int out_size, void* d_ws, size_t ws_size,
                              hipStream_t stream) {
    const float* x = (const float*)d_in[0];
    const float* W = (const float*)d_in[1];
    const float* b = (const float*)d_in[2];
    float* out = (float*)d_out;
    const int N = in_sizes[0] / D_DIM;        // 16384
    const int ntiles = N / BM;                // 512

    f16* whi = (f16*)d_ws;                         // 512 KB
    f16* wlo = whi + (size_t)E_DIM * D_DIM;        // 512 KB

    hipLaunchKernelGGL(pack_w, dim3((E_DIM * D_DIM) / (NT * 4)), dim3(NT),
                       0, stream, W, whi, wlo);
    hipLaunchKernelGGL(moe_gate_fused, dim3(ntiles), dim3(NT),
                       0, stream, x, whi, wlo, b, out, N);
}